// Round 5
// baseline (144.433 us; speedup 1.0000x reference)
//
#include <hip/hip_runtime.h>
#include <cstdint>
#include <cstddef>

#define CIN   256
#define COUT  256
#define CMID  64
#define H     64
#define W     64
#define HO    128
#define WO    128
#define BATCH 4

typedef unsigned short u16;
typedef unsigned int   u32;
typedef __attribute__((ext_vector_type(8))) __bf16 bf16x8;
typedef __attribute__((ext_vector_type(4))) float f32x4;

// Packed layouts (granule = 8 bf16 = 16 B, lane-contiguous; every MFMA
// fragment load is 4 contiguous 256B segments):
//   Xt [b][y(65)][s=kc*4+q (32)][x(65)][8ci]   row = 16640 u16
//   X2t[b][y(65)][s=kc2*4+q (8)][x(65)][8cm]   row = 4160 u16
//   WPH[t(9)][kc(8)][q(4)][co(256)][8ci]
//   WPL[t(9)][kc2(2)][q(4)][co(256)][8cm]
// y==64 is a zero guard row; x==64 a zero guard granule (boundary taps).
#define XT_ROW  16640
#define X2_ROW  4160

__device__ __forceinline__ u16 f2bf(float f) {
    u32 u = __builtin_bit_cast(u32, f);
    u += 0x7fffu + ((u >> 16) & 1u);          // RNE
    return (u16)(u >> 16);
}

// ---------------------------------------------------------------------------
// Fused prep (grid 332 = 260 input blocks + 72 weight-pack blocks).
// Input block (b, y): inx row -> bf16 (LDS + global Xt), then 1x1 bottleneck
// MFMA (W1 converted into LDS per block) -> X2t.
// Pack block (t, kc): wH/wL -> fragment-major WPH/WPL.
// ---------------------------------------------------------------------------
__global__ __launch_bounds__(256) void k_prep(const float* __restrict__ inx,
                                              const float* __restrict__ w1,
                                              const float* __restrict__ b1,
                                              const float* __restrict__ wH,
                                              const float* __restrict__ wL,
                                              u16* __restrict__ Xt,
                                              u16* __restrict__ X2t,
                                              u16* __restrict__ WPH,
                                              u16* __restrict__ WPL) {
    __shared__ u16 sX[32 * 64 * 8];               // 32 KiB [s][x][8ci]
    __shared__ u16 sW1[8 * 4 * 64 * 8];           // 32 KiB [kc][q][cm][8ci]
    const int blk = blockIdx.x;
    const int tid = threadIdx.x;

    if (blk >= BATCH * 65) {                      // ---- weight-pack blocks ----
        const int pb = blk - BATCH * 65;
        const int t = pb / 8;
        const int kc = pb % 8;
        const int co = tid;
        #pragma unroll
        for (int q = 0; q < 4; ++q) {
            u16 pk[8];
            #pragma unroll
            for (int j = 0; j < 8; ++j) {
                int ci = kc * 32 + q * 8 + j;
                pk[j] = f2bf(wH[((size_t)ci * COUT + co) * 9 + t]);
            }
            *(uint4*)(WPH + ((((size_t)t * 8 + kc) * 4 + q) * 256 + co) * 8) = *(uint4*)pk;
        }
        if (kc < 2) {
            #pragma unroll
            for (int q = 0; q < 4; ++q) {
                u16 pk[8];
                #pragma unroll
                for (int j = 0; j < 8; ++j) {
                    int cm = kc * 32 + q * 8 + j;
                    pk[j] = f2bf(wL[((size_t)cm * COUT + co) * 9 + t]);
                }
                *(uint4*)(WPL + ((((size_t)t * 2 + kc) * 4 + q) * 256 + co) * 8) = *(uint4*)pk;
            }
        }
        return;
    }

    // ---- input blocks ----
    const int b = blk / 65;
    const int y = blk % 65;
    u16* xrow  = Xt  + (size_t)(b * 65 + y) * XT_ROW;
    u16* x2row = X2t + (size_t)(b * 65 + y) * X2_ROW;
    if (y == H) {                                 // zero guard rows
        uint4 z = {0, 0, 0, 0};
        for (int i = tid; i < XT_ROW / 8; i += 256) *(uint4*)(xrow + i * 8) = z;
        for (int i = tid; i < X2_ROW / 8; i += 256) *(uint4*)(x2row + i * 8) = z;
        return;
    }

    // W1 -> LDS (coalesced float4 reads, granule-local LDS writes)
    #pragma unroll
    for (int i = 0; i < 16; ++i) {                // 4096 float4 / 256 threads
        int lin4 = i * 256 + tid;
        float4 v = ((const float4*)w1)[lin4];
        int lin = lin4 * 4;
        int cm = lin >> 8, ci = lin & 255;
        u16* dp = sW1 + (((size_t)(ci >> 3) * 64 + cm) * 8) + (ci & 7);
        dp[0] = f2bf(v.x); dp[1] = f2bf(v.y); dp[2] = f2bf(v.z); dp[3] = f2bf(v.w);
    }

    const int x = tid & 63, g0 = tid >> 6;
    #pragma unroll
    for (int gg = 0; gg < 8; ++gg) {
        const int s = gg * 4 + g0;                // s = kc*4+q, ci0 = s*8
        u16 pk[8];
        #pragma unroll
        for (int j = 0; j < 8; ++j)
            pk[j] = f2bf(inx[(((size_t)b * CIN + s * 8 + j) * H + y) * W + x]);
        uint4 v = *(uint4*)pk;
        *(uint4*)(xrow + ((size_t)s * 65 + x) * 8) = v;
        *(uint4*)(sX   + ((size_t)s * 64 + x) * 8) = v;
    }
    if (tid < 32) {                               // Xt x-guard granule
        uint4 z = {0, 0, 0, 0};
        *(uint4*)(xrow + ((size_t)tid * 65 + 64) * 8) = z;
    }
    if (tid < 8) {                                // X2t x-guard granule
        uint4 z = {0, 0, 0, 0};
        *(uint4*)(x2row + ((size_t)tid * 65 + 64) * 8) = z;
    }
    __syncthreads();

    // 1x1 bottleneck: M=64 cm x N=64 x, K=256. Wave wv -> x tile.
    const int wv = tid >> 6, lane = tid & 63, l15 = lane & 15, q = lane >> 4;
    f32x4 acc[4] = {};
    #pragma unroll
    for (int kc = 0; kc < 8; ++kc) {
        bf16x8 bfr = *(const bf16x8*)(sX + ((size_t)(kc * 4 + q) * 64 + wv * 16 + l15) * 8);
        #pragma unroll
        for (int mi = 0; mi < 4; ++mi) {
            bf16x8 af = *(const bf16x8*)(sW1 + (((size_t)kc * 4 + q) * 64 + mi * 16 + l15) * 8);
            acc[mi] = __builtin_amdgcn_mfma_f32_16x16x32_bf16(af, bfr, acc[mi], 0, 0, 0);
        }
    }
    const int xx = wv * 16 + l15;
    #pragma unroll
    for (int mi = 0; mi < 4; ++mi) {              // C row cm = mi*16+q*4+r
        const int s = mi * 2 + (q >> 1);          // = (cm>>3)
        u16 pk[4];
        #pragma unroll
        for (int r = 0; r < 4; ++r)
            pk[r] = f2bf(acc[mi][r] + b1[mi * 16 + q * 4 + r]);
        *(ushort4*)(x2row + ((size_t)s * 65 + xx) * 8 + (q & 1) * 4) = *(ushort4*)&pk[0];
    }
}

// ---------------------------------------------------------------------------
// Main accumulation: barrier-free, direct-register fragment loads.
// NR = taps in y (1 for even oy, 2 for odd).
// ---------------------------------------------------------------------------
template<int NR>
__device__ __forceinline__ void accum_all(const u16* __restrict__ Xt,
                                          const u16* __restrict__ X2t,
                                          const u16* __restrict__ WPH,
                                          const u16* __restrict__ WPL,
                                          int b, int y0, int rowR, int coLane,
                                          int q, int l15,
                                          const int* __restrict__ selE,
                                          const int* __restrict__ selO,
                                          f32x4 ce[4][4], f32x4 co_[4][4]) {
    const bf16x8 z8 = {};
    // ---- high branch: 8 K-chunks of 32 over CIN ----
    #pragma unroll 2
    for (int kc = 0; kc < 8; ++kc) {
        #pragma unroll
        for (int dy = 0; dy < NR; ++dy) {
            const int ky = (NR == 1) ? 1 : (dy ? 0 : 2);
            const u16* bp = Xt + (size_t)(b * 65 + y0 + rowR + dy) * XT_ROW
                               + ((size_t)(kc * 4 + q) * 65 + l15) * 8;
            bf16x8 be[4], bo0[4], bo1[4];
            #pragma unroll
            for (int ni = 0; ni < 4; ++ni) {
                bf16x8 b0 = *(const bf16x8*)(bp + ni * 128);
                bf16x8 b1 = *(const bf16x8*)(bp + ni * 128 + 8);
                be[ni]  = selE[ni] ? b0 : z8;     // high kept where mask==1
                bo0[ni] = selO[ni] ? b0 : z8;
                bo1[ni] = selO[ni] ? b1 : z8;
            }
            const u16* ap = WPH + ((((size_t)(ky * 3) * 8 + kc) * 4 + q) * 256 + coLane) * 8;
            #pragma unroll
            for (int mi = 0; mi < 4; ++mi) {      // kx=1 -> even cols
                bf16x8 a = *(const bf16x8*)(ap + 65536 + mi * 128);
                #pragma unroll
                for (int ni = 0; ni < 4; ++ni)
                    ce[mi][ni] = __builtin_amdgcn_mfma_f32_16x16x32_bf16(a, be[ni], ce[mi][ni], 0, 0, 0);
            }
            #pragma unroll
            for (int mi = 0; mi < 4; ++mi) {      // kx=2 -> odd cols, dx=0
                bf16x8 a = *(const bf16x8*)(ap + 131072 + mi * 128);
                #pragma unroll
                for (int ni = 0; ni < 4; ++ni)
                    co_[mi][ni] = __builtin_amdgcn_mfma_f32_16x16x32_bf16(a, bo0[ni], co_[mi][ni], 0, 0, 0);
            }
            #pragma unroll
            for (int mi = 0; mi < 4; ++mi) {      // kx=0 -> odd cols, dx=1
                bf16x8 a = *(const bf16x8*)(ap + mi * 128);
                #pragma unroll
                for (int ni = 0; ni < 4; ++ni)
                    co_[mi][ni] = __builtin_amdgcn_mfma_f32_16x16x32_bf16(a, bo1[ni], co_[mi][ni], 0, 0, 0);
            }
        }
    }
    // ---- low branch: 2 K-chunks of 32 over CMID ----
    #pragma unroll
    for (int kc = 0; kc < 2; ++kc) {
        #pragma unroll
        for (int dy = 0; dy < NR; ++dy) {
            const int ky = (NR == 1) ? 1 : (dy ? 0 : 2);
            const u16* bp = X2t + (size_t)(b * 65 + y0 + rowR + dy) * X2_ROW
                                + ((size_t)(kc * 4 + q) * 65 + l15) * 8;
            bf16x8 be[4], bo0[4], bo1[4];
            #pragma unroll
            for (int ni = 0; ni < 4; ++ni) {
                bf16x8 b0 = *(const bf16x8*)(bp + ni * 128);
                bf16x8 b1 = *(const bf16x8*)(bp + ni * 128 + 8);
                be[ni]  = selE[ni] ? z8 : b0;     // low kept where mask==0
                bo0[ni] = selO[ni] ? z8 : b0;
                bo1[ni] = selO[ni] ? z8 : b1;
            }
            const u16* ap = WPL + ((((size_t)(ky * 3) * 2 + kc) * 4 + q) * 256 + coLane) * 8;
            #pragma unroll
            for (int mi = 0; mi < 4; ++mi) {
                bf16x8 a = *(const bf16x8*)(ap + 16384 + mi * 128);
                #pragma unroll
                for (int ni = 0; ni < 4; ++ni)
                    ce[mi][ni] = __builtin_amdgcn_mfma_f32_16x16x32_bf16(a, be[ni], ce[mi][ni], 0, 0, 0);
            }
            #pragma unroll
            for (int mi = 0; mi < 4; ++mi) {
                bf16x8 a = *(const bf16x8*)(ap + 32768 + mi * 128);
                #pragma unroll
                for (int ni = 0; ni < 4; ++ni)
                    co_[mi][ni] = __builtin_amdgcn_mfma_f32_16x16x32_bf16(a, bo0[ni], co_[mi][ni], 0, 0, 0);
            }
            #pragma unroll
            for (int mi = 0; mi < 4; ++mi) {
                bf16x8 a = *(const bf16x8*)(ap + mi * 128);
                #pragma unroll
                for (int ni = 0; ni < 4; ++ni)
                    co_[mi][ni] = __builtin_amdgcn_mfma_f32_16x16x32_bf16(a, bo1[ni], co_[mi][ni], 0, 0, 0);
            }
        }
    }
}

// ---------------------------------------------------------------------------
// Main: barrier-free phase GEMM, column-exclusive accumulation.
// Grid 512 = (py, b, yP 0..31, coH). 4 waves = (rowR, coQ).
// Wave tile: co 64 (mi=4) x x 64 (ni=4) x {even,odd ox} -> ce/co_ 128 VGPR.
// ---------------------------------------------------------------------------
__global__ __launch_bounds__(256, 2) void k_main(const u16* __restrict__ Xt,
                                                 const u16* __restrict__ X2t,
                                                 const u16* __restrict__ WPH,
                                                 const u16* __restrict__ WPL,
                                                 const float* __restrict__ bH,
                                                 const float* __restrict__ bL,
                                                 const float* __restrict__ mask,
                                                 float* __restrict__ out) {
    const int blk = blockIdx.x;
    const int coH = blk & 1;
    const int yP  = (blk >> 1) & 31;
    const int b   = (blk >> 6) & 3;
    const int py  = blk >> 8;
    const int y0  = yP * 2;

    const int tid = threadIdx.x;
    const int wid = tid >> 6, lane = tid & 63, l15 = lane & 15, q = lane >> 4;
    const int rowR = wid >> 1, coQ = wid & 1;
    const int oy = 2 * (y0 + rowR) + py;
    const int coLane = coH * 128 + coQ * 64 + l15;

    // per-column branch selects (mask is exactly 0/1)
    int selE[4], selO[4];
    const float* mrow = mask + ((size_t)b * HO + oy) * WO;
    #pragma unroll
    for (int ni = 0; ni < 4; ++ni) {
        float2 mm = *(const float2*)(mrow + 2 * (ni * 16 + l15));
        selE[ni] = (mm.x != 0.f);
        selO[ni] = (mm.y != 0.f);
    }

    f32x4 ce[4][4] = {}, co_[4][4] = {};
    if (py == 0)
        accum_all<1>(Xt, X2t, WPH, WPL, b, y0, rowR, coLane, q, l15, selE, selO, ce, co_);
    else
        accum_all<2>(Xt, X2t, WPH, WPL, b, y0, rowR, coLane, q, l15, selE, selO, ce, co_);

    // ---- epilogue: add selected bias, float2 full-density stores ----
    #pragma unroll
    for (int mi = 0; mi < 4; ++mi) {
        const int cob = coH * 128 + coQ * 64 + mi * 16 + q * 4;
        float bh[4], bl[4];
        #pragma unroll
        for (int r = 0; r < 4; ++r) { bh[r] = bH[cob + r]; bl[r] = bL[cob + r]; }
        #pragma unroll
        for (int r = 0; r < 4; ++r) {
            float* orow = out + (((size_t)b * COUT + cob + r) * HO + oy) * WO;
            #pragma unroll
            for (int ni = 0; ni < 4; ++ni) {
                const int x = ni * 16 + l15;
                float2 v;
                v.x = ce[mi][ni][r]  + (selE[ni] ? bh[r] : bl[r]);
                v.y = co_[mi][ni][r] + (selO[ni] ? bh[r] : bl[r]);
                *(float2*)(orow + 2 * x) = v;
            }
        }
    }
}

// ---------------------------------------------------------------------------
extern "C" void kernel_launch(void* const* d_in, const int* in_sizes, int n_in,
                              void* d_out, int out_size, void* d_ws, size_t ws_size,
                              hipStream_t stream) {
    const float* inx    = (const float*)d_in[0];
    const float* mask   = (const float*)d_in[1];
    // d_in[2] = inv_mask (unused: mask is exactly 0/1)
    const float* w_high = (const float*)d_in[3];
    const float* b_high = (const float*)d_in[4];
    const float* w_low1 = (const float*)d_in[5];
    const float* b_low1 = (const float*)d_in[6];
    const float* w_low2 = (const float*)d_in[7];
    const float* b_low2 = (const float*)d_in[8];
    float* out = (float*)d_out;

    char* ws = (char*)d_ws;
    u16* Xt  = (u16*)(ws);                 //  8,652,800 B
    u16* X2t = (u16*)(ws + 8652800);       //  2,163,200 B
    u16* WPH = (u16*)(ws + 10816000);      //  1,179,648 B
    u16* WPL = (u16*)(ws + 11995648);      //    294,912 B  (total ~12.3 MiB)

    k_prep<<<BATCH * 65 + 72, 256, 0, stream>>>(inx, w_low1, b_low1, w_high, w_low2,
                                                Xt, X2t, WPH, WPL);
    k_main<<<512, 256, 0, stream>>>(Xt, X2t, WPH, WPL, b_high, b_low2, mask, out);
}

// Round 6
// 125.701 us; speedup vs baseline: 1.1490x; 1.1490x over previous
//
#include <hip/hip_runtime.h>
#include <cstdint>
#include <cstddef>

#define CIN   256
#define COUT  256
#define CMID  64
#define H     64
#define W     64
#define HO    128
#define WO    128
#define BATCH 4

typedef unsigned short u16;
typedef unsigned int   u32;
typedef __attribute__((ext_vector_type(8))) __bf16 bf16x8;
typedef __attribute__((ext_vector_type(4))) float f32x4;

// Packed layouts (granule = 8 bf16 = 16 B, lane-contiguous):
//   Xt [b][y(65)][s=kc*4+q (32)][x(65)][8ci]   row = 16640 u16
//   X2t[b][y(65)][s=kc2*4+q (8)][x(65)][8cm]   row = 4160 u16
//   WPH[t(9)][kc(8)][q(4)][co(256)][8ci]
//   WPL[t(9)][kc2(2)][q(4)][co(256)][8cm]
// y==64 zero guard row; x==64 zero guard granule.
#define XT_ROW  16640
#define X2_ROW  4160

#define AS1 __attribute__((address_space(1)))
#define AS3 __attribute__((address_space(3)))

// global->LDS direct 16B copy; LDS dst is wave-uniform base, HW adds lane*16.
__device__ __forceinline__ void g2l16(const void* g, const void* l) {
    __builtin_amdgcn_global_load_lds((const AS1 u32*)(uintptr_t)g,
                                     (AS3 u32*)(u32)(uintptr_t)l, 16, 0, 0);
}

__device__ __forceinline__ u16 f2bf(float f) {
    u32 u = __builtin_bit_cast(u32, f);
    u += 0x7fffu + ((u >> 16) & 1u);          // RNE
    return (u16)(u >> 16);
}

// ---------------------------------------------------------------------------
// Fused prep (grid 332 = 260 input blocks + 72 weight-pack blocks).
// ---------------------------------------------------------------------------
__global__ __launch_bounds__(256) void k_prep(const float* __restrict__ inx,
                                              const float* __restrict__ w1,
                                              const float* __restrict__ b1,
                                              const float* __restrict__ wH,
                                              const float* __restrict__ wL,
                                              u16* __restrict__ Xt,
                                              u16* __restrict__ X2t,
                                              u16* __restrict__ WPH,
                                              u16* __restrict__ WPL) {
    __shared__ u16 sX[32 * 64 * 8];               // 32 KiB [s][x][8ci]
    __shared__ u16 sW1[8 * 4 * 64 * 8];           // 32 KiB [kc][q][cm][8ci]
    const int blk = blockIdx.x;
    const int tid = threadIdx.x;

    if (blk >= BATCH * 65) {                      // ---- weight-pack blocks ----
        const int pb = blk - BATCH * 65;
        const int t = pb / 8;
        const int kc = pb % 8;
        const int co = tid;
        #pragma unroll
        for (int q = 0; q < 4; ++q) {
            u16 pk[8];
            #pragma unroll
            for (int j = 0; j < 8; ++j) {
                int ci = kc * 32 + q * 8 + j;
                pk[j] = f2bf(wH[((size_t)ci * COUT + co) * 9 + t]);
            }
            *(uint4*)(WPH + ((((size_t)t * 8 + kc) * 4 + q) * 256 + co) * 8) = *(uint4*)pk;
        }
        if (kc < 2) {
            #pragma unroll
            for (int q = 0; q < 4; ++q) {
                u16 pk[8];
                #pragma unroll
                for (int j = 0; j < 8; ++j) {
                    int cm = kc * 32 + q * 8 + j;
                    pk[j] = f2bf(wL[((size_t)cm * COUT + co) * 9 + t]);
                }
                *(uint4*)(WPL + ((((size_t)t * 2 + kc) * 4 + q) * 256 + co) * 8) = *(uint4*)pk;
            }
        }
        return;
    }

    // ---- input blocks ----
    const int b = blk / 65;
    const int y = blk % 65;
    u16* xrow  = Xt  + (size_t)(b * 65 + y) * XT_ROW;
    u16* x2row = X2t + (size_t)(b * 65 + y) * X2_ROW;
    if (y == H) {                                 // zero guard rows
        uint4 z = {0, 0, 0, 0};
        for (int i = tid; i < XT_ROW / 8; i += 256) *(uint4*)(xrow + i * 8) = z;
        for (int i = tid; i < X2_ROW / 8; i += 256) *(uint4*)(x2row + i * 8) = z;
        return;
    }

    // W1 -> LDS
    #pragma unroll
    for (int i = 0; i < 16; ++i) {                // 4096 float4 / 256 threads
        int lin4 = i * 256 + tid;
        float4 v = ((const float4*)w1)[lin4];
        int lin = lin4 * 4;
        int cm = lin >> 8, ci = lin & 255;
        u16* dp = sW1 + (((size_t)(ci >> 3) * 64 + cm) * 8) + (ci & 7);
        dp[0] = f2bf(v.x); dp[1] = f2bf(v.y); dp[2] = f2bf(v.z); dp[3] = f2bf(v.w);
    }

    const int x = tid & 63, g0 = tid >> 6;
    #pragma unroll
    for (int gg = 0; gg < 8; ++gg) {
        const int s = gg * 4 + g0;                // s = kc*4+q, ci0 = s*8
        u16 pk[8];
        #pragma unroll
        for (int j = 0; j < 8; ++j)
            pk[j] = f2bf(inx[(((size_t)b * CIN + s * 8 + j) * H + y) * W + x]);
        uint4 v = *(uint4*)pk;
        *(uint4*)(xrow + ((size_t)s * 65 + x) * 8) = v;
        *(uint4*)(sX   + ((size_t)s * 64 + x) * 8) = v;
    }
    if (tid < 32) {                               // Xt x-guard granule
        uint4 z = {0, 0, 0, 0};
        *(uint4*)(xrow + ((size_t)tid * 65 + 64) * 8) = z;
    }
    if (tid < 8) {                                // X2t x-guard granule
        uint4 z = {0, 0, 0, 0};
        *(uint4*)(x2row + ((size_t)tid * 65 + 64) * 8) = z;
    }
    __syncthreads();

    // 1x1 bottleneck: M=64 cm x N=64 x, K=256.
    const int wv = tid >> 6, lane = tid & 63, l15 = lane & 15, q = lane >> 4;
    f32x4 acc[4] = {};
    #pragma unroll
    for (int kc = 0; kc < 8; ++kc) {
        bf16x8 bfr = *(const bf16x8*)(sX + ((size_t)(kc * 4 + q) * 64 + wv * 16 + l15) * 8);
        #pragma unroll
        for (int mi = 0; mi < 4; ++mi) {
            bf16x8 af = *(const bf16x8*)(sW1 + (((size_t)kc * 4 + q) * 64 + mi * 16 + l15) * 8);
            acc[mi] = __builtin_amdgcn_mfma_f32_16x16x32_bf16(af, bfr, acc[mi], 0, 0, 0);
        }
    }
    const int xx = wv * 16 + l15;
    #pragma unroll
    for (int mi = 0; mi < 4; ++mi) {              // C row cm = mi*16+q*4+r
        const int s = mi * 2 + (q >> 1);          // = (cm>>3)
        u16 pk[4];
        #pragma unroll
        for (int r = 0; r < 4; ++r)
            pk[r] = f2bf(acc[mi][r] + b1[mi * 16 + q * 4 + r]);
        *(ushort4*)(x2row + ((size_t)s * 65 + xx) * 8 + (q & 1) * 4) = *(ushort4*)&pk[0];
    }
}

// ---------------------------------------------------------------------------
// k_main: double-buffered LDS-staged phase GEMM.
// Grid 512 = (py, b, yP 0..31, coH). 4 waves = (rowR 2 x coQ 2).
// Step = (branch, kc, dy): stage next step's A (3kx x 4q x 128co = 24KB) and
// B (2 rows x 4q x 64x = 8.2KB) while computing current from the other buffer.
// One __syncthreads per step; vmcnt drain overlapped by ~48 MFMA of compute.
// ---------------------------------------------------------------------------
#define SA_G 1536                                 // A granules per buffer
#define SB_G 520                                  // B granules per buffer (8*65)

template<int NR>
struct Step {
    __device__ static constexpr int count() { return NR * 10; }
    __device__ static bool hi(int c) { return c < NR * 8; }
    __device__ static int  kc(int c) { int cc = hi(c) ? c : c - NR * 8; return NR == 1 ? cc : cc >> 1; }
    __device__ static int  dy(int c) { int cc = hi(c) ? c : c - NR * 8; return NR == 1 ? 0 : (cc & 1); }
    __device__ static int  ky(int c) { return NR == 1 ? 1 : (dy(c) ? 0 : 2); }
};

template<int NR>
__device__ __forceinline__ void stage(int c, u16* sAb, u16* sBb,
                                      const u16* __restrict__ Xt,
                                      const u16* __restrict__ X2t,
                                      const u16* __restrict__ WPH,
                                      const u16* __restrict__ WPL,
                                      int b, int y0, int coH, int wid, int lane) {
    const bool hi = Step<NR>::hi(c);
    const int kc = Step<NR>::kc(c);
    const int dy = Step<NR>::dy(c);
    const int ky = Step<NR>::ky(c);
    const int kcn = hi ? 8 : 2;
    const u16* Wp = hi ? WPH : WPL;
    const u16* Xp = hi ? Xt : X2t;
    const size_t rowStr = hi ? XT_ROW : X2_ROW;
    // A: 24 segs of 64 granules; wave takes seg = i*4+wid
    #pragma unroll
    for (int i = 0; i < 6; ++i) {
        const int seg = i * 4 + wid;
        const int kx = seg >> 3, qq = (seg >> 1) & 3, h = seg & 1;
        const u16* src = Wp + ((((size_t)(ky * 3 + kx) * kcn + kc) * 4 + qq) * 256
                                + coH * 128 + h * 64 + lane) * 8;
        g2l16(src, sAb + ((size_t)((kx * 4 + qq) * 128 + h * 64)) * 8);
    }
    // B: 8 segs (2 rows x 4q); wave takes (r=i, q=wid)
    #pragma unroll
    for (int i = 0; i < 2; ++i) {
        const u16* src = Xp + (size_t)(b * 65 + y0 + dy + i) * rowStr
                            + ((size_t)(kc * 4 + wid) * 65 + lane) * 8;
        g2l16(src, sBb + ((size_t)(i * 4 + wid) * 65) * 8);
    }
}

template<int NR>
__device__ __forceinline__ void compute(int c, const u16* sAb, const u16* sBb,
                                        int rowR, int coQ, int q, int l15,
                                        const int* __restrict__ selE,
                                        const int* __restrict__ selO,
                                        f32x4 ce[4][4], f32x4 co_[4][4]) {
    const bool hi = Step<NR>::hi(c);
    const bf16x8 z8 = {};
    const u16* bp = sBb + (((size_t)(rowR * 4 + q)) * 65 + l15) * 8;
    bf16x8 be[4], bo0[4], bo1[4];
    #pragma unroll
    for (int ni = 0; ni < 4; ++ni) {
        bf16x8 b0 = *(const bf16x8*)(bp + ni * 128);
        bf16x8 b1 = *(const bf16x8*)(bp + ni * 128 + 8);
        const bool kE = hi ? (selE[ni] != 0) : (selE[ni] == 0);
        const bool kO = hi ? (selO[ni] != 0) : (selO[ni] == 0);
        be[ni]  = kE ? b0 : z8;
        bo0[ni] = kO ? b0 : z8;
        bo1[ni] = kO ? b1 : z8;
    }
    const u16* ap = sAb + ((size_t)(q * 128 + coQ * 64 + l15)) * 8;
    #pragma unroll
    for (int mi = 0; mi < 4; ++mi) {              // kx=1 -> even cols
        bf16x8 a = *(const bf16x8*)(ap + (1 * 512 + mi * 16) * 8);
        #pragma unroll
        for (int ni = 0; ni < 4; ++ni)
            ce[mi][ni] = __builtin_amdgcn_mfma_f32_16x16x32_bf16(a, be[ni], ce[mi][ni], 0, 0, 0);
    }
    #pragma unroll
    for (int mi = 0; mi < 4; ++mi) {              // kx=2 -> odd cols, dx=0
        bf16x8 a = *(const bf16x8*)(ap + (2 * 512 + mi * 16) * 8);
        #pragma unroll
        for (int ni = 0; ni < 4; ++ni)
            co_[mi][ni] = __builtin_amdgcn_mfma_f32_16x16x32_bf16(a, bo0[ni], co_[mi][ni], 0, 0, 0);
    }
    #pragma unroll
    for (int mi = 0; mi < 4; ++mi) {              // kx=0 -> odd cols, dx=1
        bf16x8 a = *(const bf16x8*)(ap + (mi * 16) * 8);
        #pragma unroll
        for (int ni = 0; ni < 4; ++ni)
            co_[mi][ni] = __builtin_amdgcn_mfma_f32_16x16x32_bf16(a, bo1[ni], co_[mi][ni], 0, 0, 0);
    }
}

__global__ __launch_bounds__(256, 2) void k_main(const u16* __restrict__ Xt,
                                                 const u16* __restrict__ X2t,
                                                 const u16* __restrict__ WPH,
                                                 const u16* __restrict__ WPL,
                                                 const float* __restrict__ bH,
                                                 const float* __restrict__ bL,
                                                 const float* __restrict__ mask,
                                                 float* __restrict__ out) {
    __shared__ u16 sA[2][SA_G * 8];               // 2 x 24576 B
    __shared__ u16 sB[2][SB_G * 8];               // 2 x  8320 B

    const int blk = blockIdx.x;
    const int coH = blk & 1;
    const int yP  = (blk >> 1) & 31;
    const int b   = (blk >> 6) & 3;
    const int py  = blk >> 8;
    const int y0  = yP * 2;

    const int tid = threadIdx.x;
    const int wid = tid >> 6, lane = tid & 63, l15 = lane & 15, q = lane >> 4;
    const int rowR = wid >> 1, coQ = wid & 1;
    const int oy = 2 * (y0 + rowR) + py;

    // per-column branch selects (mask is exactly 0/1)
    int selE[4], selO[4];
    const float* mrow = mask + ((size_t)b * HO + oy) * WO;
    #pragma unroll
    for (int ni = 0; ni < 4; ++ni) {
        float2 mm = *(const float2*)(mrow + 2 * (ni * 16 + l15));
        selE[ni] = (mm.x != 0.f);
        selO[ni] = (mm.y != 0.f);
    }

    if (tid < 16) {                               // zero B x-guard granules
        uint4 z = {0, 0, 0, 0};
        *(uint4*)(sB[tid >> 3] + (((size_t)(tid & 7)) * 65 + 64) * 8) = z;
    }

    f32x4 ce[4][4] = {}, co_[4][4] = {};

    if (py == 0) {
        constexpr int NS = Step<1>::count();
        stage<1>(0, sA[0], sB[0], Xt, X2t, WPH, WPL, b, y0, coH, wid, lane);
        __syncthreads();
        #pragma unroll
        for (int c = 0; c < NS; ++c) {
            if (c + 1 < NS)
                stage<1>(c + 1, sA[(c + 1) & 1], sB[(c + 1) & 1],
                         Xt, X2t, WPH, WPL, b, y0, coH, wid, lane);
            compute<1>(c, sA[c & 1], sB[c & 1], rowR, coQ, q, l15, selE, selO, ce, co_);
            __syncthreads();
        }
    } else {
        constexpr int NS = Step<2>::count();
        stage<2>(0, sA[0], sB[0], Xt, X2t, WPH, WPL, b, y0, coH, wid, lane);
        __syncthreads();
        #pragma unroll
        for (int c = 0; c < NS; ++c) {
            if (c + 1 < NS)
                stage<2>(c + 1, sA[(c + 1) & 1], sB[(c + 1) & 1],
                         Xt, X2t, WPH, WPL, b, y0, coH, wid, lane);
            compute<2>(c, sA[c & 1], sB[c & 1], rowR, coQ, q, l15, selE, selO, ce, co_);
            __syncthreads();
        }
    }

    // ---- epilogue: add selected bias, float2 full-density stores ----
    #pragma unroll
    for (int mi = 0; mi < 4; ++mi) {
        const int cob = coH * 128 + coQ * 64 + mi * 16 + q * 4;
        float bh[4], bl[4];
        #pragma unroll
        for (int r = 0; r < 4; ++r) { bh[r] = bH[cob + r]; bl[r] = bL[cob + r]; }
        #pragma unroll
        for (int r = 0; r < 4; ++r) {
            float* orow = out + (((size_t)b * COUT + cob + r) * HO + oy) * WO;
            #pragma unroll
            for (int ni = 0; ni < 4; ++ni) {
                const int x = ni * 16 + l15;
                float2 v;
                v.x = ce[mi][ni][r]  + (selE[ni] ? bh[r] : bl[r]);
                v.y = co_[mi][ni][r] + (selO[ni] ? bh[r] : bl[r]);
                *(float2*)(orow + 2 * x) = v;
            }
        }
    }
}

// ---------------------------------------------------------------------------
extern "C" void kernel_launch(void* const* d_in, const int* in_sizes, int n_in,
                              void* d_out, int out_size, void* d_ws, size_t ws_size,
                              hipStream_t stream) {
    const float* inx    = (const float*)d_in[0];
    const float* mask   = (const float*)d_in[1];
    // d_in[2] = inv_mask (unused: mask is exactly 0/1)
    const float* w_high = (const float*)d_in[3];
    const float* b_high = (const float*)d_in[4];
    const float* w_low1 = (const float*)d_in[5];
    const float* b_low1 = (const float*)d_in[6];
    const float* w_low2 = (const float*)d_in[7];
    const float* b_low2 = (const float*)d_in[8];
    float* out = (float*)d_out;

    char* ws = (char*)d_ws;
    u16* Xt  = (u16*)(ws);                 //  8,652,800 B
    u16* X2t = (u16*)(ws + 8652800);       //  2,163,200 B
    u16* WPH = (u16*)(ws + 10816000);      //  1,179,648 B
    u16* WPL = (u16*)(ws + 11995648);      //    294,912 B  (total ~12.3 MiB)

    k_prep<<<BATCH * 65 + 72, 256, 0, stream>>>(inx, w_low1, b_low1, w_high, w_low2,
                                                Xt, X2t, WPH, WPL);
    k_main<<<512, 256, 0, stream>>>(Xt, X2t, WPH, WPL, b_high, b_low2, mask, out);
}

// Round 7
// 123.483 us; speedup vs baseline: 1.1697x; 1.0180x over previous
//
#include <hip/hip_runtime.h>
#include <cstdint>
#include <cstddef>

#define CIN   256
#define COUT  256
#define CMID  64
#define H     64
#define W     64
#define HO    128
#define WO    128
#define BATCH 4

typedef unsigned short u16;
typedef unsigned int   u32;
typedef __attribute__((ext_vector_type(8))) __bf16 bf16x8;
typedef __attribute__((ext_vector_type(4))) float f32x4;

// Packed layouts (granule = 8 bf16 = 16 B, lane-contiguous):
//   Xt [b][y(65)][s=kc*4+q (32)][x(65)][8ci]   row = 16640 u16
//   X2t[b][y(65)][s=kc2*4+q (8)][x(65)][8cm]   row = 4160 u16
//   WPH[t(9)][kc(8)][q(4)][co(256)][8ci]
//   WPL[t(9)][kc2(2)][q(4)][co(256)][8cm]
// y==64 zero guard row; x==64 zero guard granule.
#define XT_ROW  16640
#define X2_ROW  4160

#define AS1 __attribute__((address_space(1)))
#define AS3 __attribute__((address_space(3)))

// global->LDS direct 16B copy; LDS dst is wave-uniform base, HW adds lane*16.
__device__ __forceinline__ void g2l16(const void* g, const void* l) {
    __builtin_amdgcn_global_load_lds((const AS1 u32*)(uintptr_t)g,
                                     (AS3 u32*)(u32)(uintptr_t)l, 16, 0, 0);
}

__device__ __forceinline__ u16 f2bf(float f) {
    u32 u = __builtin_bit_cast(u32, f);
    u += 0x7fffu + ((u >> 16) & 1u);          // RNE
    return (u16)(u >> 16);
}

// ---------------------------------------------------------------------------
// Fused prep (grid 332 = 260 input blocks + 72 weight-pack blocks).
// ---------------------------------------------------------------------------
__global__ __launch_bounds__(256) void k_prep(const float* __restrict__ inx,
                                              const float* __restrict__ w1,
                                              const float* __restrict__ b1,
                                              const float* __restrict__ wH,
                                              const float* __restrict__ wL,
                                              u16* __restrict__ Xt,
                                              u16* __restrict__ X2t,
                                              u16* __restrict__ WPH,
                                              u16* __restrict__ WPL) {
    __shared__ u16 sX[32 * 64 * 8];               // 32 KiB [s][x][8ci]
    __shared__ u16 sW1[8 * 4 * 64 * 8];           // 32 KiB [kc][q][cm][8ci]
    const int blk = blockIdx.x;
    const int tid = threadIdx.x;

    if (blk >= BATCH * 65) {                      // ---- weight-pack blocks ----
        const int pb = blk - BATCH * 65;
        const int t = pb / 8;
        const int kc = pb % 8;
        const int co = tid;
        #pragma unroll
        for (int q = 0; q < 4; ++q) {
            u16 pk[8];
            #pragma unroll
            for (int j = 0; j < 8; ++j) {
                int ci = kc * 32 + q * 8 + j;
                pk[j] = f2bf(wH[((size_t)ci * COUT + co) * 9 + t]);
            }
            *(uint4*)(WPH + ((((size_t)t * 8 + kc) * 4 + q) * 256 + co) * 8) = *(uint4*)pk;
        }
        if (kc < 2) {
            #pragma unroll
            for (int q = 0; q < 4; ++q) {
                u16 pk[8];
                #pragma unroll
                for (int j = 0; j < 8; ++j) {
                    int cm = kc * 32 + q * 8 + j;
                    pk[j] = f2bf(wL[((size_t)cm * COUT + co) * 9 + t]);
                }
                *(uint4*)(WPL + ((((size_t)t * 2 + kc) * 4 + q) * 256 + co) * 8) = *(uint4*)pk;
            }
        }
        return;
    }

    // ---- input blocks ----
    const int b = blk / 65;
    const int y = blk % 65;
    u16* xrow  = Xt  + (size_t)(b * 65 + y) * XT_ROW;
    u16* x2row = X2t + (size_t)(b * 65 + y) * X2_ROW;
    if (y == H) {                                 // zero guard rows
        uint4 z = {0, 0, 0, 0};
        for (int i = tid; i < XT_ROW / 8; i += 256) *(uint4*)(xrow + i * 8) = z;
        for (int i = tid; i < X2_ROW / 8; i += 256) *(uint4*)(x2row + i * 8) = z;
        return;
    }

    // W1 -> LDS
    #pragma unroll
    for (int i = 0; i < 16; ++i) {                // 4096 float4 / 256 threads
        int lin4 = i * 256 + tid;
        float4 v = ((const float4*)w1)[lin4];
        int lin = lin4 * 4;
        int cm = lin >> 8, ci = lin & 255;
        u16* dp = sW1 + (((size_t)(ci >> 3) * 64 + cm) * 8) + (ci & 7);
        dp[0] = f2bf(v.x); dp[1] = f2bf(v.y); dp[2] = f2bf(v.z); dp[3] = f2bf(v.w);
    }

    const int x = tid & 63, g0 = tid >> 6;
    #pragma unroll
    for (int gg = 0; gg < 8; ++gg) {
        const int s = gg * 4 + g0;                // s = kc*4+q, ci0 = s*8
        u16 pk[8];
        #pragma unroll
        for (int j = 0; j < 8; ++j)
            pk[j] = f2bf(inx[(((size_t)b * CIN + s * 8 + j) * H + y) * W + x]);
        uint4 v = *(uint4*)pk;
        *(uint4*)(xrow + ((size_t)s * 65 + x) * 8) = v;
        *(uint4*)(sX   + ((size_t)s * 64 + x) * 8) = v;
    }
    if (tid < 32) {                               // Xt x-guard granule
        uint4 z = {0, 0, 0, 0};
        *(uint4*)(xrow + ((size_t)tid * 65 + 64) * 8) = z;
    }
    if (tid < 8) {                                // X2t x-guard granule
        uint4 z = {0, 0, 0, 0};
        *(uint4*)(x2row + ((size_t)tid * 65 + 64) * 8) = z;
    }
    __syncthreads();

    // 1x1 bottleneck: M=64 cm x N=64 x, K=256.
    const int wv = tid >> 6, lane = tid & 63, l15 = lane & 15, q = lane >> 4;
    f32x4 acc[4] = {};
    #pragma unroll
    for (int kc = 0; kc < 8; ++kc) {
        bf16x8 bfr = *(const bf16x8*)(sX + ((size_t)(kc * 4 + q) * 64 + wv * 16 + l15) * 8);
        #pragma unroll
        for (int mi = 0; mi < 4; ++mi) {
            bf16x8 af = *(const bf16x8*)(sW1 + (((size_t)kc * 4 + q) * 64 + mi * 16 + l15) * 8);
            acc[mi] = __builtin_amdgcn_mfma_f32_16x16x32_bf16(af, bfr, acc[mi], 0, 0, 0);
        }
    }
    const int xx = wv * 16 + l15;
    #pragma unroll
    for (int mi = 0; mi < 4; ++mi) {              // C row cm = mi*16+q*4+r
        const int s = mi * 2 + (q >> 1);          // = (cm>>3)
        u16 pk[4];
        #pragma unroll
        for (int r = 0; r < 4; ++r)
            pk[r] = f2bf(acc[mi][r] + b1[mi * 16 + q * 4 + r]);
        *(ushort4*)(x2row + ((size_t)s * 65 + xx) * 8 + (q & 1) * 4) = *(ushort4*)&pk[0];
    }
}

// ---------------------------------------------------------------------------
// k_main: double-buffered LDS-staged phase GEMM, address-select masking.
// Grid 512 = (py, b, yP 0..31, coH). 4 waves = (rowR 2 x coQ 2).
// Step = (branch, kc, dy): stage next step's A (24KB) + B (2 rows, 8.2KB)
// while computing current from the other buffer. Masking is done by
// redirecting the LDS read address of deselected column-fragments to a
// 16B zero granule (broadcast read, 1 VALU per select vs 8 for data cndmask).
// ---------------------------------------------------------------------------
#define SA_G 1536                                 // A granules per buffer
#define SB_G 520                                  // B granules per buffer (8*65)

template<int NR>
struct Step {
    __device__ static constexpr int count() { return NR * 10; }
    __device__ static bool hi(int c) { return c < NR * 8; }
    __device__ static int  kc(int c) { int cc = hi(c) ? c : c - NR * 8; return NR == 1 ? cc : cc >> 1; }
    __device__ static int  dy(int c) { int cc = hi(c) ? c : c - NR * 8; return NR == 1 ? 0 : (cc & 1); }
    __device__ static int  ky(int c) { return NR == 1 ? 1 : (dy(c) ? 0 : 2); }
};

template<int NR>
__device__ __forceinline__ void stage(int c, u16* sAb, u16* sBb,
                                      const u16* __restrict__ Xt,
                                      const u16* __restrict__ X2t,
                                      const u16* __restrict__ WPH,
                                      const u16* __restrict__ WPL,
                                      int b, int y0, int coH, int wid, int lane) {
    const bool hi = Step<NR>::hi(c);
    const int kc = Step<NR>::kc(c);
    const int dy = Step<NR>::dy(c);
    const int ky = Step<NR>::ky(c);
    const int kcn = hi ? 8 : 2;
    const u16* Wp = hi ? WPH : WPL;
    const u16* Xp = hi ? Xt : X2t;
    const size_t rowStr = hi ? XT_ROW : X2_ROW;
    // A: 24 segs of 64 granules; wave takes seg = i*4+wid
    #pragma unroll
    for (int i = 0; i < 6; ++i) {
        const int seg = i * 4 + wid;
        const int kx = seg >> 3, qq = (seg >> 1) & 3, h = seg & 1;
        const u16* src = Wp + ((((size_t)(ky * 3 + kx) * kcn + kc) * 4 + qq) * 256
                                + coH * 128 + h * 64 + lane) * 8;
        g2l16(src, sAb + ((size_t)((kx * 4 + qq) * 128 + h * 64)) * 8);
    }
    // B: 8 segs (2 rows x 4 q-chunks); wave wid stages q-chunk wid of each row
    #pragma unroll
    for (int i = 0; i < 2; ++i) {
        const u16* src = Xp + (size_t)(b * 65 + y0 + dy + i) * rowStr
                            + ((size_t)(kc * 4 + wid) * 65 + lane) * 8;
        g2l16(src, sBb + ((size_t)(i * 4 + wid) * 65) * 8);
    }
}

template<int NR>
__device__ __forceinline__ void compute(int c, const u16* sAb, const u16* sBb,
                                        const u16* zg,
                                        int rowR, int coQ, int q, int l15,
                                        const int* __restrict__ selE,
                                        const int* __restrict__ selO,
                                        f32x4 ce[4][4], f32x4 co_[4][4]) {
    const bool hi = Step<NR>::hi(c);
    const u16* bp = sBb + (((size_t)(rowR * 4 + q)) * 65 + l15) * 8;
    bf16x8 be[4], bo0[4], bo1[4];
    #pragma unroll
    for (int ni = 0; ni < 4; ++ni) {
        // address-select: deselected columns read the zero granule (broadcast)
        const bool kE = hi ? (selE[ni] != 0) : (selE[ni] == 0);
        const bool kO = hi ? (selO[ni] != 0) : (selO[ni] == 0);
        const u16* p0 = bp + ni * 128;
        be[ni]  = *(const bf16x8*)(kE ? p0 : zg);
        bo0[ni] = *(const bf16x8*)(kO ? p0 : zg);
        bo1[ni] = *(const bf16x8*)(kO ? p0 + 8 : zg);
    }
    const u16* ap = sAb + ((size_t)(q * 128 + coQ * 64 + l15)) * 8;
    #pragma unroll
    for (int mi = 0; mi < 4; ++mi) {              // kx=1 -> even cols
        bf16x8 a = *(const bf16x8*)(ap + (1 * 512 + mi * 16) * 8);
        #pragma unroll
        for (int ni = 0; ni < 4; ++ni)
            ce[mi][ni] = __builtin_amdgcn_mfma_f32_16x16x32_bf16(a, be[ni], ce[mi][ni], 0, 0, 0);
    }
    #pragma unroll
    for (int mi = 0; mi < 4; ++mi) {              // kx=2 -> odd cols, dx=0
        bf16x8 a = *(const bf16x8*)(ap + (2 * 512 + mi * 16) * 8);
        #pragma unroll
        for (int ni = 0; ni < 4; ++ni)
            co_[mi][ni] = __builtin_amdgcn_mfma_f32_16x16x32_bf16(a, bo0[ni], co_[mi][ni], 0, 0, 0);
    }
    #pragma unroll
    for (int mi = 0; mi < 4; ++mi) {              // kx=0 -> odd cols, dx=1
        bf16x8 a = *(const bf16x8*)(ap + (mi * 16) * 8);
        #pragma unroll
        for (int ni = 0; ni < 4; ++ni)
            co_[mi][ni] = __builtin_amdgcn_mfma_f32_16x16x32_bf16(a, bo1[ni], co_[mi][ni], 0, 0, 0);
    }
}

__global__ __launch_bounds__(256, 2) void k_main(const u16* __restrict__ Xt,
                                                 const u16* __restrict__ X2t,
                                                 const u16* __restrict__ WPH,
                                                 const u16* __restrict__ WPL,
                                                 const float* __restrict__ bH,
                                                 const float* __restrict__ bL,
                                                 const float* __restrict__ mask,
                                                 float* __restrict__ out) {
    __shared__ u16 sA[2][SA_G * 8];               // 2 x 24576 B
    __shared__ u16 sB[2][SB_G * 8];               // 2 x  8320 B
    __shared__ u16 sZ[8];                         // 16 B zero granule

    const int blk = blockIdx.x;
    const int coH = blk & 1;
    const int yP  = (blk >> 1) & 31;
    const int b   = (blk >> 6) & 3;
    const int py  = blk >> 8;
    const int y0  = yP * 2;

    const int tid = threadIdx.x;
    const int wid = tid >> 6, lane = tid & 63, l15 = lane & 15, q = lane >> 4;
    const int rowR = wid >> 1, coQ = wid & 1;
    const int oy = 2 * (y0 + rowR) + py;

    // per-column branch selects (mask is exactly 0/1)
    int selE[4], selO[4];
    const float* mrow = mask + ((size_t)b * HO + oy) * WO;
    #pragma unroll
    for (int ni = 0; ni < 4; ++ni) {
        float2 mm = *(const float2*)(mrow + 2 * (ni * 16 + l15));
        selE[ni] = (mm.x != 0.f);
        selO[ni] = (mm.y != 0.f);
    }

    if (tid < 16) {                               // zero B x-guard granules
        uint4 z = {0, 0, 0, 0};
        *(uint4*)(sB[tid >> 3] + (((size_t)(tid & 7)) * 65 + 64) * 8) = z;
    }
    if (tid == 16) *(uint4*)sZ = (uint4){0, 0, 0, 0};

    f32x4 ce[4][4] = {}, co_[4][4] = {};

    if (py == 0) {
        constexpr int NS = Step<1>::count();
        stage<1>(0, sA[0], sB[0], Xt, X2t, WPH, WPL, b, y0, coH, wid, lane);
        __syncthreads();
        #pragma unroll
        for (int c = 0; c < NS; ++c) {
            if (c + 1 < NS)
                stage<1>(c + 1, sA[(c + 1) & 1], sB[(c + 1) & 1],
                         Xt, X2t, WPH, WPL, b, y0, coH, wid, lane);
            compute<1>(c, sA[c & 1], sB[c & 1], sZ, rowR, coQ, q, l15, selE, selO, ce, co_);
            __syncthreads();
        }
    } else {
        constexpr int NS = Step<2>::count();
        stage<2>(0, sA[0], sB[0], Xt, X2t, WPH, WPL, b, y0, coH, wid, lane);
        __syncthreads();
        #pragma unroll
        for (int c = 0; c < NS; ++c) {
            if (c + 1 < NS)
                stage<2>(c + 1, sA[(c + 1) & 1], sB[(c + 1) & 1],
                         Xt, X2t, WPH, WPL, b, y0, coH, wid, lane);
            compute<2>(c, sA[c & 1], sB[c & 1], sZ, rowR, coQ, q, l15, selE, selO, ce, co_);
            __syncthreads();
        }
    }

    // ---- epilogue: add selected bias, float2 full-density stores ----
    #pragma unroll
    for (int mi = 0; mi < 4; ++mi) {
        const int cob = coH * 128 + coQ * 64 + mi * 16 + q * 4;
        float bh[4], bl[4];
        #pragma unroll
        for (int r = 0; r < 4; ++r) { bh[r] = bH[cob + r]; bl[r] = bL[cob + r]; }
        #pragma unroll
        for (int r = 0; r < 4; ++r) {
            float* orow = out + (((size_t)b * COUT + cob + r) * HO + oy) * WO;
            #pragma unroll
            for (int ni = 0; ni < 4; ++ni) {
                const int x = ni * 16 + l15;
                float2 v;
                v.x = ce[mi][ni][r]  + (selE[ni] ? bh[r] : bl[r]);
                v.y = co_[mi][ni][r] + (selO[ni] ? bh[r] : bl[r]);
                *(float2*)(orow + 2 * x) = v;
            }
        }
    }
}

// ---------------------------------------------------------------------------
extern "C" void kernel_launch(void* const* d_in, const int* in_sizes, int n_in,
                              void* d_out, int out_size, void* d_ws, size_t ws_size,
                              hipStream_t stream) {
    const float* inx    = (const float*)d_in[0];
    const float* mask   = (const float*)d_in[1];
    // d_in[2] = inv_mask (unused: mask is exactly 0/1)
    const float* w_high = (const float*)d_in[3];
    const float* b_high = (const float*)d_in[4];
    const float* w_low1 = (const float*)d_in[5];
    const float* b_low1 = (const float*)d_in[6];
    const float* w_low2 = (const float*)d_in[7];
    const float* b_low2 = (const float*)d_in[8];
    float* out = (float*)d_out;

    char* ws = (char*)d_ws;
    u16* Xt  = (u16*)(ws);                 //  8,652,800 B
    u16* X2t = (u16*)(ws + 8652800);       //  2,163,200 B
    u16* WPH = (u16*)(ws + 10816000);      //  1,179,648 B
    u16* WPL = (u16*)(ws + 11995648);      //    294,912 B  (total ~12.3 MiB)

    k_prep<<<BATCH * 65 + 72, 256, 0, stream>>>(inx, w_low1, b_low1, w_high, w_low2,
                                                Xt, X2t, WPH, WPL);
    k_main<<<512, 256, 0, stream>>>(Xt, X2t, WPH, WPL, b_high, b_low2, mask, out);
}